// Round 6
// baseline (215.541 us; speedup 1.0000x reference)
//
#include <hip/hip_runtime.h>

// Conv1d as implicit GEMM on MFMA bf16 — R10.
// out[n,f,t] = sum_{c,k} x[n,c,t+k] * w[f,c,k] + b[f]
// N=32, C=64, W=4096, F=128, WW=64, out_W=4033. Output fp32.
//
// R10 vs R9:
//  * MFMA shape 16x16x32 -> 32x32x16 (measured ceiling 2075 -> 2495 TF;
//    floor 66 -> 55 us). Half the MFMA instructions, same acc reg count.
//  * Register budget fixed: acc 128 + A 40 + B 32 + addr ~= 220 < 256.
//    No cross-iteration B ping-pong (R9's spilled ~30 MB; WRITE 96 MB).
//  * Tap-pair sharing at stride 32: A(tile i, k+32) == A(tile i+1, k);
//    5 A-frags per c16-group serve 2 taps x 4 t-tiles.
//  * Full-width x tile (320 x 72 shorts, 46 KB): NO mid-loop barriers at
//    all (64 free-running iterations). Staging writes now 16 lanes/row,
//    banks all-distinct (was 8-way conflicted).
//  * B still global->register from frag-packed L2-resident w (1 MB).
//  * Epilogue: 64-row transpose buffer (66.6 KB, unioned), 2 rounds.

#define C_TOT    64
#define F_TOT    128
#define KW       64
#define OUT_W    4033
#define W_IN     4096
#define N_BATCH  32
#define T_BLK    256
#define XROWS    320
#define XSTR     72            // xt row stride (shorts) = 144 B
#define TRS      260           // epilogue transpose row stride (dwords)

typedef __attribute__((ext_vector_type(8)))  short short8;
typedef __attribute__((ext_vector_type(16))) float f32x16;

__device__ inline unsigned short f32_to_bf16(float f) {
  unsigned int u = __float_as_uint(f);
  u += 0x7FFF + ((u >> 16) & 1);
  return (unsigned short)(u >> 16);
}

// ---- prep: w[f][c][k] fp32 -> frag-packed bf16 for 32x32x16 ----
// frag = ((hc*32 + k1)*16) + tap*8 + fh2*4 + ftile*2 + g16
//   k = k1 + 32*tap
//   f = fh2*64 + ftile*32 + (lane&31)          (B col = lane&31)
//   c = hc*32 + g16*16 + (lane>>5)*8 + e       (B k-elem = (lane>>5)*8+e)
// short index = frag*512 + lane*8 + e   (1024 frags x 1 KB = 1 MB)
__global__ __launch_bounds__(256) void conv1d_prep(
    const float* __restrict__ w, unsigned short* __restrict__ wsw) {
  int j = blockIdx.x * 256 + threadIdx.x;     // 131072 ushort4 jobs
  if (j < 131072) {
    int e4    = (j & 1) * 4;
    int lane  = (j >> 1) & 63;
    int frag  = j >> 7;
    int g16   = frag & 1;
    int ftile = (frag >> 1) & 1;
    int fh2   = (frag >> 2) & 1;
    int tap   = (frag >> 3) & 1;
    int k1    = (frag >> 4) & 31;
    int hc    = (frag >> 9) & 1;
    int k  = k1 + 32 * tap;
    int f  = fh2 * 64 + ftile * 32 + (lane & 31);
    int c0 = hc * 32 + g16 * 16 + (lane >> 5) * 8 + e4;
    const float* src = w + ((size_t)f * C_TOT + c0) * KW + k;
    ushort4 o;
    o.x = f32_to_bf16(src[0 * KW]);
    o.y = f32_to_bf16(src[1 * KW]);
    o.z = f32_to_bf16(src[2 * KW]);
    o.w = f32_to_bf16(src[3 * KW]);
    *(ushort4*)&wsw[(size_t)j * 4] = o;
  }
}

// ---------------- main GEMM ----------------
__global__ __launch_bounds__(256, 2) void conv1d_mfma(
    const float* __restrict__ x, const unsigned short* __restrict__ wsw,
    const float* __restrict__ b, float* __restrict__ out) {
  __shared__ union SM {
    unsigned short xt[XROWS * XSTR];   // 46.1 KB  x tile bf16 [t][c]
    float tr[64 * TRS];                // 66.6 KB  epilogue overlay
  } sm;

  const int tid   = threadIdx.x;
  const int lane  = tid & 63;
  const int row32 = lane & 31;   // A row / B col / D col
  const int kg    = lane >> 5;   // k-elem half (8 elems each)
  const int wv    = tid >> 6;    // 0..3
  const int fh2   = wv & 1;      // f half (64 f)
  const int th    = wv >> 1;     // t half (128 t)
  const int n     = blockIdx.y;
  const int t0    = blockIdx.x * T_BLK;

  const float* xrowb = x + (size_t)n * C_TOT * W_IN;
  const short8* wf   = (const short8*)wsw;

  f32x16 acc[4][2];              // [t-tile][f-tile]
#pragma unroll
  for (int tt = 0; tt < 4; ++tt)
#pragma unroll
    for (int ft = 0; ft < 2; ++ft) acc[tt][ft] = (f32x16)0.0f;

  // ---- stage x: 320 rows x 64 c, bf16, once ----
  // job jj: ti = jj>>4 (row), cl4 = (jj&15)*4 (c group). 16 lanes share a
  // row -> ushort4 writes hit 32 distinct banks (conflict-free).
#pragma unroll 4
  for (int r = 0; r < 20; ++r) {
    int jj  = r * 256 + tid;
    int cl4 = (jj & 15) * 4;
    int ti  = jj >> 4;
    int gt  = t0 + ti;
    const float* src = xrowb + (size_t)cl4 * W_IN + gt;
    float4 v = {0.f, 0.f, 0.f, 0.f};
    if (gt < W_IN) {
      v.x = src[0];
      v.y = src[W_IN];
      v.z = src[2 * W_IN];
      v.w = src[3 * W_IN];
    }
    ushort4 o;
    o.x = f32_to_bf16(v.x); o.y = f32_to_bf16(v.y);
    o.z = f32_to_bf16(v.z); o.w = f32_to_bf16(v.w);
    *(ushort4*)&sm.xt[ti * XSTR + cl4] = o;
  }
  __syncthreads();

  // ---- main loop: 64 barrier-free iterations ----
  for (int hc = 0; hc < 2; ++hc) {
    for (int k1 = 0; k1 < 32; ++k1) {
      // B: 8 frags global->reg (L2-resident), g16-major issue order
      const short8* fb = wf + ((size_t)((hc * 32 + k1) * 16 + fh2 * 4)) * 64 + lane;
      short8 B[2][2][2];           // [g16][tap][ftile]
#pragma unroll
      for (int g = 0; g < 2; ++g)
#pragma unroll
        for (int tap = 0; tap < 2; ++tap)
#pragma unroll
          for (int ft = 0; ft < 2; ++ft)
            B[g][tap][ft] = fb[(tap * 8 + ft * 2 + g) * 64];

      // A: 10 frags; rows 128*th + 32*j + k1 + row32, j=0..4
      const unsigned short* ap =
          &sm.xt[(128 * th + k1 + row32) * XSTR + hc * 32 + kg * 8];
      short8 A[2][5];
#pragma unroll
      for (int g = 0; g < 2; ++g)
#pragma unroll
        for (int jr = 0; jr < 5; ++jr)
          A[g][jr] = *(const short8*)&ap[jr * 32 * XSTR + g * 16];

      __builtin_amdgcn_s_setprio(1);
#pragma unroll
      for (int g = 0; g < 2; ++g)
#pragma unroll
        for (int tap = 0; tap < 2; ++tap)
#pragma unroll
          for (int tt = 0; tt < 4; ++tt)
#pragma unroll
            for (int ft = 0; ft < 2; ++ft)
              acc[tt][ft] = __builtin_amdgcn_mfma_f32_32x32x16_bf16(
                  A[g][tt + tap], B[g][tap][ft], acc[tt][ft], 0, 0, 0);
      __builtin_amdgcn_s_setprio(0);
    }
  }
  __syncthreads();               // xt dead; tr overlay begins

  // ---- epilogue: LDS transpose to [f][t], coalesced float4 stores ----
  // D layout (32x32): col = lane&31 (f), row = (r&3) + 8*(r>>2) + 4*kg (t)
  // t_loc = 128*th + 32*tt + 8*g + 4*kg + (r&3);  f = fh2*64 + jr*32 + row32
  const int slot_w = fh2 * 32 + row32;  // 64 f-slots
  const int s_r    = tid >> 2;          // f-slot for reads (0..63)
  const int seg    = tid & 3;
  const size_t ob  = ((size_t)n * F_TOT) * OUT_W;

#pragma unroll
  for (int jr = 0; jr < 2; ++jr) {      // round jr handles ftile == jr
#pragma unroll
    for (int tt = 0; tt < 4; ++tt)
#pragma unroll
      for (int g = 0; g < 4; ++g) {
        float4 vv;
        vv.x = acc[tt][jr][4 * g + 0];
        vv.y = acc[tt][jr][4 * g + 1];
        vv.z = acc[tt][jr][4 * g + 2];
        vv.w = acc[tt][jr][4 * g + 3];
        int tl = 128 * th + 32 * tt + 8 * g + 4 * kg;
        *(float4*)&sm.tr[slot_w * TRS + tl] = vv;
      }
    __syncthreads();
    const int f = (s_r >> 5) * 64 + jr * 32 + (s_r & 31);
    const float bias = b[f];
    const size_t obf = ob + (size_t)f * OUT_W;
#pragma unroll
    for (int j2 = 0; j2 < 16; ++j2) {
      int tl = seg * 4 + 16 * j2;
      float4 vv = *(const float4*)&sm.tr[s_r * TRS + tl];
      vv.x += bias; vv.y += bias; vv.z += bias; vv.w += bias;
      int t = t0 + tl;
      if (t + 3 < OUT_W) {
        *(float4*)&out[obf + t] = vv;
      } else {
        float e[4] = {vv.x, vv.y, vv.z, vv.w};
#pragma unroll
        for (int u = 0; u < 4; ++u)
          if (t + u < OUT_W) out[obf + t + u] = e[u];
      }
    }
    __syncthreads();
  }
}

extern "C" void kernel_launch(void* const* d_in, const int* in_sizes, int n_in,
                              void* d_out, int out_size, void* d_ws, size_t ws_size,
                              hipStream_t stream) {
  const float* x = (const float*)d_in[0];
  const float* w = (const float*)d_in[1];
  const float* b = (const float*)d_in[2];
  float* out = (float*)d_out;

  unsigned short* wsw = (unsigned short*)d_ws;   // 1 MB frag-packed bf16 w

  conv1d_prep<<<512, 256, 0, stream>>>(w, wsw);

  dim3 grid((OUT_W + T_BLK - 1) / T_BLK, N_BATCH);  // 16 x 32 = 512 blocks
  conv1d_mfma<<<grid, 256, 0, stream>>>(x, wsw, b, out);
}

// Round 7
// 189.256 us; speedup vs baseline: 1.1389x; 1.1389x over previous
//
#include <hip/hip_runtime.h>

// Conv1d as implicit GEMM on MFMA bf16 — R11.
// out[n,f,t] = sum_{c,k} x[n,c,t+k] * w[f,c,k] + b[f]
// N=32, C=64, W=4096, F=128, WW=64, out_W=4033. Output fp32.
//
// R11 = R9 (best: 114 us, 48% of dense pipe) + spill fix.
//  * R9's 30 MB scratch traffic (WRITE 96 vs 66 MB) came from forced
//    liveness: A[9] (36 regs) live across the whole 64-MFMA cluster, on
//    top of acc 128 + B 48 -> ~227 forced-live > what the allocator can
//    schedule under 256.
//  * Fix: ms-major ROLLING A-window. Stage ms: prefetch A[ms+2], then
//    4 MFMA tap0 (A[ms]) + 4 MFMA tap1 (A[ms+1]). Only 3 A-frags live
//    (12 regs); each ds_read covered by 8 MFMAs (~129 cyc >= LDS lat).
//    All slot indices compile-time (no scratch demotion).
//  * Forced-live now ~203: acc 128 + Bt0/Bt1/Bn 48 + A 12 + addr.
//  * R10's 32x32 shape REVERTED (lost the B ping-pong -> 35% of pipe).
//  * Unchanged from R9: barrier-free main loop, B global->register from
//    frag-packed L2-resident w, setprio around MFMA cluster, c-half
//    switch at gi==31, LDS-transpose epilogue.

#define C_TOT    64
#define F_TOT    128
#define KW       64
#define OUT_W    4033
#define W_IN     4096
#define N_BATCH  32
#define T_BLK    256
#define XROWS    320
#define XSTR     40            // xt row stride (shorts) = 80 B
#define TRS      260           // epilogue transpose row stride (dwords)

typedef __attribute__((ext_vector_type(8))) short  short8;
typedef __attribute__((ext_vector_type(4))) float  floatx4;

__device__ inline unsigned short f32_to_bf16(float f) {
  unsigned int u = __float_as_uint(f);
  u += 0x7FFF + ((u >> 16) & 1);
  return (unsigned short)(u >> 16);
}

// ---- prep: w[f][c][k] fp32 -> frag-packed bf16 ----
// frag id = ((gi*2 + tap)*2 + fh2)*4 + ft ; lane = q*16 + col ; elem e 0..7
//   k = (gi&15) + 32*((gi>>4)&1) + 16*tap
//   f = fh2*64 + ft*16 + col
//   c = (gi>>5)*32 + q*8 + e
// short index = frag*512 + lane*8 + e   (total 1 MB, no padding)
__global__ __launch_bounds__(256) void conv1d_prep(
    const float* __restrict__ w, unsigned short* __restrict__ wsw) {
  int j = blockIdx.x * 256 + threadIdx.x;     // 131072 ushort4 jobs
  if (j < 131072) {
    int e4  = (j & 1) * 4;
    int col = (j >> 1) & 15;
    int q   = (j >> 5) & 3;
    int ft  = (j >> 7) & 3;
    int fh2 = (j >> 9) & 1;
    int tap = (j >> 10) & 1;
    int gi  = j >> 11;
    int k   = (gi & 15) + 32 * ((gi >> 4) & 1) + 16 * tap;
    int f   = fh2 * 64 + ft * 16 + col;
    int c0  = (gi >> 5) * 32 + q * 8 + e4;
    const float* src = w + ((size_t)f * C_TOT + c0) * KW + k;
    ushort4 o;
    o.x = f32_to_bf16(src[0 * KW]);
    o.y = f32_to_bf16(src[1 * KW]);
    o.z = f32_to_bf16(src[2 * KW]);
    o.w = f32_to_bf16(src[3 * KW]);
    *(ushort4*)&wsw[(size_t)j * 4] = o;
  }
}

// ---------------- main GEMM ----------------
__global__ __launch_bounds__(256, 2) void conv1d_mfma(
    const float* __restrict__ x, const unsigned short* __restrict__ wsw,
    const float* __restrict__ b, float* __restrict__ out) {
  __shared__ union SM {
    unsigned short xt[XROWS * XSTR];   // 25.6 KB  x tile bf16 [t][c-half]
    float tr[32 * TRS];                // 33.3 KB  epilogue overlay
  } sm;

  const int tid  = threadIdx.x;
  const int lane = tid & 63;
  const int q    = lane >> 4;    // 0..3
  const int col  = lane & 15;
  const int wv   = tid >> 6;     // 0..3
  const int n    = blockIdx.y;
  const int t0   = blockIdx.x * T_BLK;
  const int fh2  = wv & 1;       // f half (64 f)
  const int th   = wv >> 1;      // t half (128 t)

  const float* xrowb = x + (size_t)n * C_TOT * W_IN;
  const short8* wf = (const short8*)wsw;   // fragment granularity

  floatx4 acc[8][4];             // [ms][ft]
#pragma unroll
  for (int ms = 0; ms < 8; ++ms)
#pragma unroll
    for (int ft = 0; ft < 4; ++ft) acc[ms][ft] = (floatx4)0.0f;

  // x stage for one c-half: c-strided dword loads -> ushort4 writes
#define STAGE_X(hc_)                                                           \
  {                                                                            \
    _Pragma("unroll")                                                          \
    for (int r = 0; r < 10; ++r) {                                             \
      int ti = (r % 5) * 64 + (tid & 63);                                      \
      int cl = ((r / 5) * 4 + (tid >> 6)) * 4;                                 \
      int gt = t0 + ti;                                                        \
      const float* src = xrowb + (size_t)((hc_) * 32 + cl) * W_IN + gt;        \
      float4 v = {0.f, 0.f, 0.f, 0.f};                                         \
      if (gt < W_IN) {                                                         \
        v.x = src[0];                                                          \
        v.y = src[W_IN];                                                       \
        v.z = src[2 * W_IN];                                                   \
        v.w = src[3 * W_IN];                                                   \
      }                                                                        \
      ushort4 o;                                                               \
      o.x = f32_to_bf16(v.x); o.y = f32_to_bf16(v.y);                          \
      o.z = f32_to_bf16(v.z); o.w = f32_to_bf16(v.w);                          \
      *(ushort4*)&sm.xt[ti * XSTR + cl] = o;                                   \
    }                                                                          \
  }

  // frag index: ((gi*2 + tap)*2 + fh2)*256 + ft*64 + lane  (short8 units)
#define BFRAG(gi_, tap_, ft_) \
  wf[(size_t)(((gi_) * 2 + (tap_)) * 2 + fh2) * 256 + (ft_) * 64 + lane]

  // One iteration: taps (k1, k1+16) of c-half gi>>5.
  // Bt0_ holds tap0 frags (prefetched last iter); Bn_ receives next tap0.
  // Rolling A-window: 3 slots, compile-time indices only.
#define BODY(gi_, Bt0_, Bn_)                                                   \
  {                                                                            \
    const int k1 = ((gi_) & 15) + 32 * (((gi_) >> 4) & 1);                     \
    short8 Bt1[4];                                                             \
    _Pragma("unroll")                                                          \
    for (int ft = 0; ft < 4; ++ft) Bt1[ft] = BFRAG(gi_, 1, ft);                \
    const unsigned short* ap = &sm.xt[(128 * th + col + k1) * XSTR + q * 8];   \
    short8 As[3];                                                              \
    As[0] = *(const short8*)&ap[0];                                            \
    As[1] = *(const short8*)&ap[1 * 16 * XSTR];                                \
    if ((gi_) + 1 < 64) {                                                      \
      _Pragma("unroll")                                                        \
      for (int ft = 0; ft < 4; ++ft) Bn_[ft] = BFRAG((gi_) + 1, 0, ft);        \
    }                                                                          \
    __builtin_amdgcn_s_setprio(1);                                             \
    _Pragma("unroll")                                                          \
    for (int ms = 0; ms < 8; ++ms) {                                           \
      if (ms + 2 <= 8)                                                         \
        As[(ms + 2) % 3] = *(const short8*)&ap[(ms + 2) * 16 * XSTR];          \
      _Pragma("unroll")                                                        \
      for (int ft = 0; ft < 4; ++ft)                                           \
        acc[ms][ft] = __builtin_amdgcn_mfma_f32_16x16x32_bf16(                 \
            As[ms % 3], Bt0_[ft], acc[ms][ft], 0, 0, 0);                       \
      _Pragma("unroll")                                                        \
      for (int ft = 0; ft < 4; ++ft)                                           \
        acc[ms][ft] = __builtin_amdgcn_mfma_f32_16x16x32_bf16(                 \
            As[(ms + 1) % 3], Bt1[ft], acc[ms][ft], 0, 0, 0);                  \
    }                                                                          \
    __builtin_amdgcn_s_setprio(0);                                             \
  }

  // prologue: stage x c-half 0, preload gi=0 tap0 frags
  STAGE_X(0)
  short8 B0[4], B1[4];
#pragma unroll
  for (int ft = 0; ft < 4; ++ft) B0[ft] = BFRAG(0, 0, ft);
  __syncthreads();

  for (int g2 = 0; g2 < 32; ++g2) {
    const int gi = 2 * g2;
    BODY(gi, B0, B1)
    BODY(gi + 1, B1, B0)
    if (gi + 1 == 31) {          // c-half switch (xt readers all done)
      __syncthreads();
      STAGE_X(1)
      __syncthreads();
    }
  }
  __syncthreads();               // waves may drift: resync before tr overlay

  // ---- epilogue: LDS transpose to [f][t], coalesced float4 stores ----
  // D layout: t_loc = 128*th + 16*ms + 4*q + r, f = 64*fh2 + 16*ft + col
  const int fs_w  = fh2 * 16 + col;     // f-slot for writes (0..31)
  const int fs_r  = tid >> 3;           // f-slot for reads (0..31)
  const int seg   = tid & 7;
  const int f_r   = (fs_r >> 4) * 64 + (fs_r & 15);
  const size_t ob = ((size_t)n * F_TOT) * OUT_W;

#pragma unroll
  for (int j = 0; j < 4; ++j) {         // round j handles ft == j (COMPILE-TIME)
#pragma unroll
    for (int ms = 0; ms < 8; ++ms) {
      float4 vv;
      vv.x = acc[ms][j][0];
      vv.y = acc[ms][j][1];
      vv.z = acc[ms][j][2];
      vv.w = acc[ms][j][3];
      int tl = 128 * th + 16 * ms + 4 * q;
      *(float4*)&sm.tr[fs_w * TRS + tl] = vv;
    }
    __syncthreads();
    const int f = f_r + 16 * j;
    const float bias = b[f];
    const size_t obf = ob + (size_t)f * OUT_W;
#pragma unroll
    for (int j2 = 0; j2 < 8; ++j2) {
      int tl = seg * 4 + 32 * j2;
      float4 vv = *(const float4*)&sm.tr[fs_r * TRS + tl];
      vv.x += bias; vv.y += bias; vv.z += bias; vv.w += bias;
      int t = t0 + tl;
      if (t + 3 < OUT_W) {
        *(float4*)&out[obf + t] = vv;
      } else {
        float e[4] = {vv.x, vv.y, vv.z, vv.w};
#pragma unroll
        for (int u = 0; u < 4; ++u)
          if (t + u < OUT_W) out[obf + t + u] = e[u];
      }
    }
    __syncthreads();
  }
}

extern "C" void kernel_launch(void* const* d_in, const int* in_sizes, int n_in,
                              void* d_out, int out_size, void* d_ws, size_t ws_size,
                              hipStream_t stream) {
  const float* x = (const float*)d_in[0];
  const float* w = (const float*)d_in[1];
  const float* b = (const float*)d_in[2];
  float* out = (float*)d_out;

  unsigned short* wsw = (unsigned short*)d_ws;   // 1 MB frag-packed bf16 w

  conv1d_prep<<<512, 256, 0, stream>>>(w, wsw);

  dim3 grid((OUT_W + T_BLK - 1) / T_BLK, N_BATCH);  // 16 x 32 = 512 blocks
  conv1d_mfma<<<grid, 256, 0, stream>>>(x, wsw, b, out);
}

// Round 8
// 185.822 us; speedup vs baseline: 1.1599x; 1.0185x over previous
//
#include <hip/hip_runtime.h>

// Conv1d as implicit GEMM on MFMA bf16 — R12.
// out[n,f,t] = sum_{c,k} x[n,c,t+k] * w[f,c,k] + b[f]
// N=32, C=64, W=4096, F=128, WW=64, out_W=4033. Output fp32.
//
// R12 = R9 schedule + register-pressure discipline.
//  * R10 (no spill at nominal 215) vs R9/R11 (spill at 203-227): runtime
//    loop back-edges are pressure dams; macro-unrolled double-bodies let
//    the scheduler hoist loads and inflate liveness. So: runtime gi-loop,
//    ONE body/iter, loop-carried Bt0 (explicit move), sched_barrier(0)
//    between tap passes.
//  * Tap-SEQUENTIAL passes (R9 order): Bt1 issued at body top, consumed
//    after 32 MFMAs (~525 cyc >= L2 latency). next-Bt0 issued at tap1
//    start, consumed next body. No exposed B latency (R11's bug).
//  * Rolling 3-slot A-window per pass, compile-time indices; tap1 pass
//    re-reads A1..A8 (16 ds_reads/BODY total). Peak forced-live ~192.
//  * Unchanged: frag-packed B global->reg (L2-resident 1 MB), barrier-free
//    main loop, c-half xt (25.6 KB), setprio, LDS-transpose epilogue.

#define C_TOT    64
#define F_TOT    128
#define KW       64
#define OUT_W    4033
#define W_IN     4096
#define N_BATCH  32
#define T_BLK    256
#define XROWS    320
#define XSTR     40            // xt row stride (shorts) = 80 B
#define TRS      260           // epilogue transpose row stride (dwords)

typedef __attribute__((ext_vector_type(8))) short  short8;
typedef __attribute__((ext_vector_type(4))) float  floatx4;

__device__ inline unsigned short f32_to_bf16(float f) {
  unsigned int u = __float_as_uint(f);
  u += 0x7FFF + ((u >> 16) & 1);
  return (unsigned short)(u >> 16);
}

// ---- prep: w[f][c][k] fp32 -> frag-packed bf16 (same as R9/R11) ----
// frag id = ((gi*2 + tap)*2 + fh2)*4 + ft ; lane = q*16 + col ; elem e 0..7
//   k = (gi&15) + 32*((gi>>4)&1) + 16*tap
//   f = fh2*64 + ft*16 + col
//   c = (gi>>5)*32 + q*8 + e
// short index = frag*512 + lane*8 + e   (total 1 MB, no padding)
__global__ __launch_bounds__(256) void conv1d_prep(
    const float* __restrict__ w, unsigned short* __restrict__ wsw) {
  int j = blockIdx.x * 256 + threadIdx.x;     // 131072 ushort4 jobs
  if (j < 131072) {
    int e4  = (j & 1) * 4;
    int col = (j >> 1) & 15;
    int q   = (j >> 5) & 3;
    int ft  = (j >> 7) & 3;
    int fh2 = (j >> 9) & 1;
    int tap = (j >> 10) & 1;
    int gi  = j >> 11;
    int k   = (gi & 15) + 32 * ((gi >> 4) & 1) + 16 * tap;
    int f   = fh2 * 64 + ft * 16 + col;
    int c0  = (gi >> 5) * 32 + q * 8 + e4;
    const float* src = w + ((size_t)f * C_TOT + c0) * KW + k;
    ushort4 o;
    o.x = f32_to_bf16(src[0 * KW]);
    o.y = f32_to_bf16(src[1 * KW]);
    o.z = f32_to_bf16(src[2 * KW]);
    o.w = f32_to_bf16(src[3 * KW]);
    *(ushort4*)&wsw[(size_t)j * 4] = o;
  }
}

// ---------------- main GEMM ----------------
__global__ __launch_bounds__(256, 2) void conv1d_mfma(
    const float* __restrict__ x, const unsigned short* __restrict__ wsw,
    const float* __restrict__ b, float* __restrict__ out) {
  __shared__ union SM {
    unsigned short xt[XROWS * XSTR];   // 25.6 KB  x tile bf16 [t][c-half]
    float tr[32 * TRS];                // 33.3 KB  epilogue overlay
  } sm;

  const int tid  = threadIdx.x;
  const int lane = tid & 63;
  const int q    = lane >> 4;    // 0..3
  const int col  = lane & 15;
  const int wv   = tid >> 6;     // 0..3
  const int n    = blockIdx.y;
  const int t0   = blockIdx.x * T_BLK;
  const int fh2  = wv & 1;       // f half (64 f)
  const int th   = wv >> 1;      // t half (128 t)

  const float* xrowb = x + (size_t)n * C_TOT * W_IN;
  // per-thread w pointer: frag(gi,tap,ft) = wp[gi*1024 + tap*512 + ft*64]
  const short8* wp = (const short8*)wsw + fh2 * 256 + lane;

  floatx4 acc[8][4];             // [ms][ft]
#pragma unroll
  for (int ms = 0; ms < 8; ++ms)
#pragma unroll
    for (int ft = 0; ft < 4; ++ft) acc[ms][ft] = (floatx4)0.0f;

  // x stage for one c-half: c-strided dword loads -> ushort4 writes
#define STAGE_X(hc_)                                                           \
  {                                                                            \
    _Pragma("unroll")                                                          \
    for (int r = 0; r < 10; ++r) {                                             \
      int ti = (r % 5) * 64 + (tid & 63);                                      \
      int cl = ((r / 5) * 4 + (tid >> 6)) * 4;                                 \
      int gt = t0 + ti;                                                        \
      const float* src = xrowb + (size_t)((hc_) * 32 + cl) * W_IN + gt;        \
      float4 v = {0.f, 0.f, 0.f, 0.f};                                         \
      if (gt < W_IN) {                                                         \
        v.x = src[0];                                                          \
        v.y = src[W_IN];                                                       \
        v.z = src[2 * W_IN];                                                   \
        v.w = src[3 * W_IN];                                                   \
      }                                                                        \
      ushort4 o;                                                               \
      o.x = f32_to_bf16(v.x); o.y = f32_to_bf16(v.y);                          \
      o.z = f32_to_bf16(v.z); o.w = f32_to_bf16(v.w);                          \
      *(ushort4*)&sm.xt[ti * XSTR + cl] = o;                                   \
    }                                                                          \
  }

  // prologue: stage x c-half 0, preload gi=0 tap0 frags
  STAGE_X(0)
  short8 Bt0[4];
#pragma unroll
  for (int ft = 0; ft < 4; ++ft) Bt0[ft] = wp[ft * 64];
  __syncthreads();

  for (int gi = 0; gi < 64; ++gi) {
    const int k1 = (gi & 15) + 32 * ((gi >> 4) & 1);   // taps (k1, k1+16)

    // issue Bt1 (this body's tap1): consumed after the 32-MFMA tap0 pass
    short8 Bt1[4];
#pragma unroll
    for (int ft = 0; ft < 4; ++ft) Bt1[ft] = wp[512 + ft * 64];

    const unsigned short* ap = &sm.xt[(128 * th + col + k1) * XSTR + q * 8];

    // ---- tap0 pass: stage ms uses A[ms]; rolling 3-slot window ----
    short8 As[3];
    As[0] = *(const short8*)&ap[0];                    // A0 -> slot 0
    As[1] = *(const short8*)&ap[1 * 16 * XSTR];        // A1 -> slot 1
    __builtin_amdgcn_s_setprio(1);
#pragma unroll
    for (int ms = 0; ms < 8; ++ms) {
      if (ms < 6)                                      // A[ms+2] -> slot (ms+2)%3
        As[(ms + 2) % 3] = *(const short8*)&ap[(ms + 2) * 16 * XSTR];
#pragma unroll
      for (int ft = 0; ft < 4; ++ft)
        acc[ms][ft] = __builtin_amdgcn_mfma_f32_16x16x32_bf16(
            As[ms % 3], Bt0[ft], acc[ms][ft], 0, 0, 0);
    }
    __builtin_amdgcn_s_setprio(0);
    __builtin_amdgcn_sched_barrier(0);                 // pass boundary dam

    // issue next body's Bt0: consumed next iteration (after back-edge)
    const short8* wn = (gi < 63) ? wp + 1024 : wp;
    short8 Bn[4];
#pragma unroll
    for (int ft = 0; ft < 4; ++ft) Bn[ft] = wn[ft * 64];

    // ---- tap1 pass: stage ms uses A[ms+1]; slot (ms+1)%3 ----
    short8 Az[3];
    Az[1] = *(const short8*)&ap[1 * 16 * XSTR];        // A1 -> slot 1
    Az[2] = *(const short8*)&ap[2 * 16 * XSTR];        // A2 -> slot 2
    __builtin_amdgcn_s_setprio(1);
#pragma unroll
    for (int ms = 0; ms < 8; ++ms) {
      if (ms < 6)                                      // A[ms+3] -> slot ms%3
        Az[ms % 3] = *(const short8*)&ap[(ms + 3) * 16 * XSTR];
#pragma unroll
      for (int ft = 0; ft < 4; ++ft)
        acc[ms][ft] = __builtin_amdgcn_mfma_f32_16x16x32_bf16(
            Az[(ms + 1) % 3], Bt1[ft], acc[ms][ft], 0, 0, 0);
    }
    __builtin_amdgcn_s_setprio(0);

    // carry Bn -> Bt0 across the back-edge (compile-time indices)
#pragma unroll
    for (int ft = 0; ft < 4; ++ft) Bt0[ft] = Bn[ft];
    wp += 1024;

    if (gi == 31) {              // c-half switch (xt readers all done)
      __syncthreads();
      STAGE_X(1)
      __syncthreads();
    }
  }
  __syncthreads();               // waves may drift: resync before tr overlay

  // ---- epilogue: LDS transpose to [f][t], coalesced float4 stores ----
  // D layout: t_loc = 128*th + 16*ms + 4*q + r, f = 64*fh2 + 16*ft + col
  const int fs_w  = fh2 * 16 + col;     // f-slot for writes (0..31)
  const int fs_r  = tid >> 3;           // f-slot for reads (0..31)
  const int seg   = tid & 7;
  const int f_r   = (fs_r >> 4) * 64 + (fs_r & 15);
  const size_t ob = ((size_t)n * F_TOT) * OUT_W;

#pragma unroll
  for (int j = 0; j < 4; ++j) {         // round j handles ft == j (COMPILE-TIME)
#pragma unroll
    for (int ms = 0; ms < 8; ++ms) {
      float4 vv;
      vv.x = acc[ms][j][0];
      vv.y = acc[ms][j][1];
      vv.z = acc[ms][j][2];
      vv.w = acc[ms][j][3];
      int tl = 128 * th + 16 * ms + 4 * q;
      *(float4*)&sm.tr[fs_w * TRS + tl] = vv;
    }
    __syncthreads();
    const int f = f_r + 16 * j;
    const float bias = b[f];
    const size_t obf = ob + (size_t)f * OUT_W;
#pragma unroll
    for (int j2 = 0; j2 < 8; ++j2) {
      int tl = seg * 4 + 32 * j2;
      float4 vv = *(const float4*)&sm.tr[fs_r * TRS + tl];
      vv.x += bias; vv.y += bias; vv.z += bias; vv.w += bias;
      int t = t0 + tl;
      if (t + 3 < OUT_W) {
        *(float4*)&out[obf + t] = vv;
      } else {
        float e[4] = {vv.x, vv.y, vv.z, vv.w};
#pragma unroll
        for (int u = 0; u < 4; ++u)
          if (t + u < OUT_W) out[obf + t + u] = e[u];
      }
    }
    __syncthreads();
  }
}

extern "C" void kernel_launch(void* const* d_in, const int* in_sizes, int n_in,
                              void* d_out, int out_size, void* d_ws, size_t ws_size,
                              hipStream_t stream) {
  const float* x = (const float*)d_in[0];
  const float* w = (const float*)d_in[1];
  const float* b = (const float*)d_in[2];
  float* out = (float*)d_out;

  unsigned short* wsw = (unsigned short*)d_ws;   // 1 MB frag-packed bf16 w

  conv1d_prep<<<512, 256, 0, stream>>>(w, wsw);

  dim3 grid((OUT_W + T_BLK - 1) / T_BLK, N_BATCH);  // 16 x 32 = 512 blocks
  conv1d_mfma<<<grid, 256, 0, stream>>>(x, wsw, b, out);
}